// Round 12
// baseline (145.800 us; speedup 1.0000x reference)
//
#include <hip/hip_runtime.h>

// Problem constants
#define HW 4096           // H*W
#define CHW 262144        // C*H*W
#define OUT_ELEMS 4194304 // B*C*H*W
#define FLT_BIG 3.4e38f

typedef __attribute__((ext_vector_type(8))) short  short8;   // MFMA A/B frag (4 VGPR)
typedef __attribute__((ext_vector_type(4))) float  floatx4;  // MFMA C/D frag
typedef __attribute__((ext_vector_type(4))) int    intx4;

// ws layout (no zero-init needed -- every byte read is written first):
//   [0,2048)        enorm f32[512]
//   [4096,135168)   planes_frag u16 (128 KB, fragment-major split-bf16 codebook)
//   [135168,151552) ws_sse double[2048]  (per-block SSE, plain stores)
//   [151552,184320) part u32[16][512]    (per-hist-block partial histograms)

__device__ __forceinline__ unsigned bf16_rne(float f) {
    unsigned u = __float_as_uint(f);
    return (u + 0x7FFFu + ((u >> 16) & 1u)) >> 16;  // RNE bf16 bits
}

__device__ __forceinline__ void split8(const float* f, intx4* hi, intx4* lo) {
    unsigned h[4], l[4];
#pragma unroll
    for (int j = 0; j < 4; ++j) {
        const unsigned h0 = bf16_rne(f[2 * j]);
        const unsigned h1 = bf16_rne(f[2 * j + 1]);
        const float hf0 = __uint_as_float(h0 << 16);
        const float hf1 = __uint_as_float(h1 << 16);
        const unsigned l0 = bf16_rne(f[2 * j] - hf0);
        const unsigned l1 = bf16_rne(f[2 * j + 1] - hf1);
        h[j] = h0 | (h1 << 16);
        l[j] = l0 | (l1 << 16);
    }
    *hi = intx4{(int)h[0], (int)h[1], (int)h[2], (int)h[3]};
    *lo = intx4{(int)l[0], (int)l[1], (int)l[2], (int)l[3]};
}

// prep: 16 blocks x 256 threads; 32 codes/block. Fragment-major split-bf16
// codebook + exact fp32 enorm. (Unchanged since R9.)
__global__ void vq_prep(const float* __restrict__ emb,
                        unsigned short* __restrict__ pfrag,
                        float* __restrict__ enorm) {
    const int t = threadIdx.x;
    const int lane = t & 63;
#pragma unroll
    for (int i = 0; i < 8; ++i) {
        const int f    = (i << 8) + t;
        const int code = (blockIdx.x << 5) + (f >> 6);  // wave-uniform
        const int c    = lane;
        const float v  = emb[(code << 6) + c];          // 256B coalesced
        const unsigned hb = bf16_rne(v);
        const float hf    = __uint_as_float(hb << 16);
        const unsigned lb = bf16_rne(v - hf);
        const int nc = code >> 6, grp = (code & 63) >> 4, n = code & 15;
        const int q = (c & 31) >> 3, o = c & 7;
        const int jh = c >> 5;        // eh element e=c
        const int jl = 2 + (c >> 5);  // el element e=64+c
        pfrag[((((size_t)(nc*4 + jh)*4 + grp)*4 + q)*16 + n)*8 + o] = (unsigned short)hb;
        pfrag[((((size_t)(nc*4 + jl)*4 + grp)*4 + q)*16 + n)*8 + o] = (unsigned short)lb;
        float s = v * v;
#pragma unroll
        for (int off = 32; off > 0; off >>= 1) s += __shfl_xor(s, off, 64);
        if (lane == 0) enorm[code] = s;
    }
}

// Main: 2048 blocks x 256 threads; 32 rows/block (half a (b,h) stripe).
// R12: wave wv covers ALL 32 rows (2 M-tiles) x code-QUARTER wv (16 codes of
// each 64-chunk). Same MFMA count as R11 (12/chunk) but half the B-fragment
// loads (4 KB/row vs 8): per-wave VMEM traffic was the R11 accounting gap
// (512 MB aggregate L2). Block count & serial chain unchanged from R11.
__global__ __launch_bounds__(256)
void vq_main(const float* __restrict__ x_in, const float* __restrict__ emb,
             const unsigned short* __restrict__ pfrag,
             const float* __restrict__ enorm,
             float* __restrict__ out, float* __restrict__ idx_out,
             double* __restrict__ ws_sse) {
    __shared__ float  b1s[4][32], b2s[4][32];
    __shared__ int    i1s[4][32], i2s[4][32];
    __shared__ int    c1i[32], c2i[32], qidx[32];
    __shared__ double parts[8][32];
    __shared__ double ls_red[4];

    const int t     = threadIdx.x;
    const int lane  = t & 63;
    const int wv    = t >> 6;          // code-quarter id
    const int col   = lane & 15;
    const int quad  = lane >> 4;
    const int blk   = blockIdx.x;
    const int ncol0 = wv << 4;         // code base within each 64-chunk
    const int half = blk & 1;          // which 32-w half of the stripe
    const int bh = blk >> 1;
    const int b = bh >> 6, h = bh & 63;
    const float* xb = x_in + (size_t)b * CHW + h * 64 + (half << 5);

    // ---- A-frags: both 16-row M-tiles, direct from BCHW global (coalesced),
    // split-bf16, register-resident ----
    short8 Ah[2][2], Al[2][2];
#pragma unroll
    for (int m = 0; m < 2; ++m) {
        const int w = (m << 4) + col;
#pragma unroll
        for (int u = 0; u < 2; ++u) {
            float f[8];
#pragma unroll
            for (int j = 0; j < 8; ++j) {
                const int c = (u << 5) + (quad << 3) + j;
                f[j] = xb[(size_t)c * HW + w];
            }
            intx4 hi, lo;
            split8(f, &hi, &lo);
            Ah[m][u] = __builtin_bit_cast(short8, hi);
            Al[m][u] = __builtin_bit_cast(short8, lo);
        }
    }

    float B1[8], B2[8]; int I1[8], I2[8];
#pragma unroll
    for (int s = 0; s < 8; ++s) { B1[s] = FLT_BIG; B2[s] = FLT_BIG; I1[s] = 0x3FFFFFFF; I2[s] = 0x3FFFFFFF; }

    // fragment base: lane*16 within the quarter's 1 KB unit (grp = wv)
    const char* pf = (const char*)pfrag + (size_t)lane * 16 + ((size_t)wv << 10);

#pragma unroll 2
    for (int nc = 0; nc < 8; ++nc) {
        const char* base = pf + ((size_t)nc << 14);
        const int K0 = nc << 6;
        const float en = enorm[K0 + ncol0 + col];

        floatx4 a0{0.f,0.f,0.f,0.f}, a1{0.f,0.f,0.f,0.f};
#define BLD(j) (*(const short8*)(base + ((j) << 12)))
        {   // j=0: eh c[0,32) -> Ah[.][0] + Al[.][0]
            const short8 bv = BLD(0);
            a0 = __builtin_amdgcn_mfma_f32_16x16x32_bf16(Ah[0][0], bv, a0, 0, 0, 0);
            a1 = __builtin_amdgcn_mfma_f32_16x16x32_bf16(Ah[1][0], bv, a1, 0, 0, 0);
            a0 = __builtin_amdgcn_mfma_f32_16x16x32_bf16(Al[0][0], bv, a0, 0, 0, 0);
            a1 = __builtin_amdgcn_mfma_f32_16x16x32_bf16(Al[1][0], bv, a1, 0, 0, 0);
        }
        {   // j=1: eh c[32,64) -> Ah[.][1] + Al[.][1]
            const short8 bv = BLD(1);
            a0 = __builtin_amdgcn_mfma_f32_16x16x32_bf16(Ah[0][1], bv, a0, 0, 0, 0);
            a1 = __builtin_amdgcn_mfma_f32_16x16x32_bf16(Ah[1][1], bv, a1, 0, 0, 0);
            a0 = __builtin_amdgcn_mfma_f32_16x16x32_bf16(Al[0][1], bv, a0, 0, 0, 0);
            a1 = __builtin_amdgcn_mfma_f32_16x16x32_bf16(Al[1][1], bv, a1, 0, 0, 0);
        }
        {   // j=2: el c[0,32) -> Ah[.][0] only
            const short8 bv = BLD(2);
            a0 = __builtin_amdgcn_mfma_f32_16x16x32_bf16(Ah[0][0], bv, a0, 0, 0, 0);
            a1 = __builtin_amdgcn_mfma_f32_16x16x32_bf16(Ah[1][0], bv, a1, 0, 0, 0);
        }
        {   // j=3: el c[32,64) -> Ah[.][1] only
            const short8 bv = BLD(3);
            a0 = __builtin_amdgcn_mfma_f32_16x16x32_bf16(Ah[0][1], bv, a0, 0, 0, 0);
            a1 = __builtin_amdgcn_mfma_f32_16x16x32_bf16(Ah[1][1], bv, a1, 0, 0, 0);
        }
#undef BLD

        // top-2 update; slot s = m*4+reg (8 slots = 2 M-tiles x 4 C-regs);
        // codes ascend across chunks -> strict < keeps first occurrence.
        const int code = K0 + ncol0 + col;
#pragma unroll
        for (int m = 0; m < 2; ++m) {
            const floatx4 av = m ? a1 : a0;
#pragma unroll
            for (int reg = 0; reg < 4; ++reg) {
                const float d = fmaf(-2.f, av[reg], en);
                const int s = (m << 2) + reg;
                if (d < B1[s])      { B2[s] = B1[s]; I2[s] = I1[s]; B1[s] = d; I1[s] = code; }
                else if (d < B2[s]) { B2[s] = d; I2[s] = code; }
            }
        }
    }

    // ---- cross-lane top-2 butterfly over col bits (disjoint code sets per
    // lane, explicit index tie-break = first-occurrence) ----
#pragma unroll
    for (int off = 1; off <= 8; off <<= 1) {
#pragma unroll
        for (int s = 0; s < 8; ++s) {
            const float ob1 = __shfl_xor(B1[s], off, 64);
            const int   oi1 = __shfl_xor(I1[s], off, 64);
            const float ob2 = __shfl_xor(B2[s], off, 64);
            const int   oi2 = __shfl_xor(I2[s], off, 64);
            if (ob1 < B1[s] || (ob1 == B1[s] && oi1 < I1[s])) {
                float nb2; int ni2;
                if (B1[s] < ob2 || (B1[s] == ob2 && I1[s] < oi2)) { nb2 = B1[s]; ni2 = I1[s]; }
                else                                              { nb2 = ob2;  ni2 = oi2; }
                B1[s] = ob1; I1[s] = oi1; B2[s] = nb2; I2[s] = ni2;
            } else if (ob1 < B2[s] || (ob1 == B2[s] && oi1 < I2[s])) {
                B2[s] = ob1; I2[s] = oi1;
            }
        }
    }
    // publish per (quarter, row): row = m*16 + quad*4 + reg; disjoint slots
    if (col == 0) {
#pragma unroll
        for (int s = 0; s < 8; ++s) {
            const int row = ((s >> 2) << 4) + (quad << 2) + (s & 3);
            b1s[wv][row] = B1[s]; b2s[wv][row] = B2[s];
            i1s[wv][row] = I1[s]; i2s[wv][row] = I2[s];
        }
    }
    __syncthreads();

    // ---- merge the 4 quarter top-2 lists -> approx top-2 per row ----
    if (t < 32) {
        const int r = t;
        float b1 = b1s[0][r], b2 = b2s[0][r];
        int   i1 = i1s[0][r], i2 = i2s[0][r];
#pragma unroll
        for (int q = 1; q < 4; ++q) {
            const float c1 = b1s[q][r]; const int j1 = i1s[q][r];
            const float c2 = b2s[q][r]; const int j2 = i2s[q][r];
            if (c1 < b1 || (c1 == b1 && j1 < i1))      { b2 = b1; i2 = i1; b1 = c1; i1 = j1; }
            else if (c1 < b2 || (c1 == b2 && j1 < i2)) { b2 = c1; i2 = j1; }
            if (c2 < b2 || (c2 == b2 && j2 < i2))      { b2 = c2; i2 = j2; }
        }
        c1i[r] = i1; c2i[r] = i2;
    }
    __syncthreads();

    // ---- unconditional 8-way-parallel exact fp64 verify of both candidates:
    // thread group k = t>>5 -> candidate (k&1), c-quarter (k>>1), 16 c each ----
    {
        const int r  = t & 31;
        const int k  = t >> 5;
        const int cq = k >> 1;
        const int code = (k & 1) ? c2i[r] : c1i[r];
        const float* ep = emb + ((size_t)code << 6) + (cq << 4);
        const float* xq = xb + r;   // lanes r consecutive -> coalesced
        double d0 = 0.0, d1 = 0.0;
#pragma unroll
        for (int cc = 0; cc < 16; cc += 2) {
            const int c = (cq << 4) + cc;
            const double f0 = (double)xq[(size_t)c * HW]       - (double)ep[cc];
            const double f1 = (double)xq[(size_t)(c + 1) * HW] - (double)ep[cc + 1];
            d0 = fma(f0, f0, d0);
            d1 = fma(f1, f1, d1);
        }
        parts[k][r] = d0 + d1;
    }
    __syncthreads();
    if (t < 32) {
        const double d1 = parts[0][t] + parts[2][t] + parts[4][t] + parts[6][t];
        const double d2 = parts[1][t] + parts[3][t] + parts[5][t] + parts[7][t];
        int i1 = c1i[t];
        const int i2 = c2i[t];
        if (d2 < d1 || (d2 == d1 && i2 < i1)) i1 = i2; // lowest-index tie-break
        qidx[t] = i1;
        idx_out[(blk << 5) + t] = (float)i1;
    }
    __syncthreads();

    // ---- epilogue: quantized out (coalesced along w) + per-block SSE ----
    {
        const int r  = t & 31;
        const int c0 = (t >> 5) << 3;    // 8 channels per thread-group
        const float* xp = xb + r;
        float*       op = out + (size_t)b * CHW + h * 64 + (half << 5) + r;
        const float* eq = emb + ((size_t)qidx[r] << 6);
        float sse_local = 0.f;
#pragma unroll
        for (int cc = 0; cc < 8; ++cc) {
            const int c = c0 + cc;
            const float qc = eq[c];
            const float dx = qc - xp[(size_t)c * HW];
            sse_local = fmaf(dx, dx, sse_local);
            op[(size_t)c * HW] = qc;
        }
#pragma unroll
        for (int off = 32; off > 0; off >>= 1)
            sse_local += __shfl_down(sse_local, off, 64);
        if (lane == 0) ls_red[wv] = (double)sse_local;
        __syncthreads();
        if (t == 0)
            ws_sse[blk] = (ls_red[0] + ls_red[1]) + (ls_red[2] + ls_red[3]);  // plain store
    }
}

// hist: 16 blocks x 256 threads; LDS histogram of 4096 indices each, plain
// partial-store. Kernel-boundary ordering provides coherence (R9-proven).
__global__ void vq_hist(const float* __restrict__ idx_out,
                        unsigned* __restrict__ part) {
    __shared__ unsigned hs[512];
    const int t = threadIdx.x;
    hs[t] = 0u; hs[t + 256] = 0u;
    __syncthreads();
    const float4* ip = (const float4*)(idx_out + (blockIdx.x << 12));
#pragma unroll
    for (int i = 0; i < 4; ++i) {
        const float4 v = ip[(i << 8) + t];    // coalesced
        atomicAdd(&hs[(int)v.x], 1u);         // LDS atomics
        atomicAdd(&hs[(int)v.y], 1u);
        atomicAdd(&hs[(int)v.z], 1u);
        atomicAdd(&hs[(int)v.w], 1u);
    }
    __syncthreads();
    unsigned* pp = part + (blockIdx.x << 9);
    pp[t] = hs[t]; pp[t + 256] = hs[t + 256];  // coalesced plain stores
}

// scal: 1 block x 512 threads. Partial hists -> perplexity; ws_sse ->
// commitment; weight -> active codes.
__global__ void vq_scal(const unsigned* __restrict__ part,
                        const double* __restrict__ ws_sse,
                        const float* __restrict__ weight,
                        float* __restrict__ scal) {
    __shared__ double redt[8], reds[8];
    __shared__ int    redi[8];
    const int k = threadIdx.x;       // 0..511 = code
    const int lane = k & 63, wv = k >> 6;
    unsigned cnt = 0;
#pragma unroll
    for (int p = 0; p < 16; ++p) cnt += part[(p << 9) + k];   // coalesced per p
    const double pr = (double)cnt / 65536.0;
    double term = pr * log(pr + 1e-10);
    double ssep = 0.0;
#pragma unroll
    for (int j = 0; j < 4; ++j) ssep += ws_sse[k + (j << 9)];
    int act = (weight[k] >= 0.01f) ? 1 : 0;
#pragma unroll
    for (int off = 32; off > 0; off >>= 1) {
        term += __shfl_down(term, off, 64);
        ssep += __shfl_down(ssep, off, 64);
        act  += __shfl_down(act,  off, 64);
    }
    if (lane == 0) { redt[wv] = term; reds[wv] = ssep; redi[wv] = act; }
    __syncthreads();
    if (k == 0) {
        double s = 0.0, ss = 0.0; int a = 0;
#pragma unroll
        for (int i = 0; i < 8; ++i) { s += redt[i]; ss += reds[i]; a += redi[i]; }
        scal[0] = (float)(ss / 4194304.0);  // commitment_loss
        scal[1] = (float)exp(-s);           // perplexity
        scal[2] = (float)a;                 // active_codes
    }
}

extern "C" void kernel_launch(void* const* d_in, const int* in_sizes, int n_in,
                              void* d_out, int out_size, void* d_ws, size_t ws_size,
                              hipStream_t stream) {
    const float* x      = (const float*)d_in[0];  // [16,64,64,64] fp32
    const float* emb    = (const float*)d_in[1];  // [512,64] fp32
    const float* weight = (const float*)d_in[2];  // [512] fp32

    float* out = (float*)d_out;
    float*          enorm  = (float*)d_ws;
    unsigned short* pfrag  = (unsigned short*)((char*)d_ws + 4096);
    double*         ws_sse = (double*)((char*)d_ws + 135168);
    unsigned*       part   = (unsigned*)((char*)d_ws + 151552);

    float* scal    = out + OUT_ELEMS;      // commitment, perplexity, active
    float* idx_out = out + OUT_ELEMS + 3;  // indices as float [65536]

    vq_prep<<<16, 256, 0, stream>>>(emb, pfrag, enorm);
    vq_main<<<2048, 256, 0, stream>>>(x, emb, pfrag, enorm, out, idx_out, ws_sse);
    vq_hist<<<16, 256, 0, stream>>>(idx_out, part);
    vq_scal<<<1, 512, 0, stream>>>(part, ws_sse, weight, scal);
}

// Round 13
// 128.434 us; speedup vs baseline: 1.1352x; 1.1352x over previous
//
#include <hip/hip_runtime.h>

// Problem constants
#define HW 4096           // H*W
#define CHW 262144        // C*H*W
#define OUT_ELEMS 4194304 // B*C*H*W
#define FLT_BIG 3.4e38f

typedef __attribute__((ext_vector_type(8))) short  short8;   // MFMA A/B frag (4 VGPR)
typedef __attribute__((ext_vector_type(4))) float  floatx4;  // MFMA C/D frag
typedef __attribute__((ext_vector_type(4))) int    intx4;

// ws layout (no zero-init needed -- every byte read is written first):
//   [0,2048)        enorm f32[512]
//   [4096,135168)   planes_frag u16 (128 KB, fragment-major split-bf16 codebook)
//   [135168,167936) ws_sse double[4096]  (per-block SSE, plain stores)
//   [167936,200704) part u32[16][512]    (per-hist-block partial histograms)

__device__ __forceinline__ unsigned bf16_rne(float f) {
    unsigned u = __float_as_uint(f);
    return (u + 0x7FFFu + ((u >> 16) & 1u)) >> 16;  // RNE bf16 bits
}

__device__ __forceinline__ void split8(const float* f, intx4* hi, intx4* lo) {
    unsigned h[4], l[4];
#pragma unroll
    for (int j = 0; j < 4; ++j) {
        const unsigned h0 = bf16_rne(f[2 * j]);
        const unsigned h1 = bf16_rne(f[2 * j + 1]);
        const float hf0 = __uint_as_float(h0 << 16);
        const float hf1 = __uint_as_float(h1 << 16);
        const unsigned l0 = bf16_rne(f[2 * j] - hf0);
        const unsigned l1 = bf16_rne(f[2 * j + 1] - hf1);
        h[j] = h0 | (h1 << 16);
        l[j] = l0 | (l1 << 16);
    }
    *hi = intx4{(int)h[0], (int)h[1], (int)h[2], (int)h[3]};
    *lo = intx4{(int)l[0], (int)l[1], (int)l[2], (int)l[3]};
}

// prep: 16 blocks x 256 threads; 32 codes/block. Fragment-major split-bf16
// codebook + exact fp32 enorm. (Unchanged since R9.)
__global__ void vq_prep(const float* __restrict__ emb,
                        unsigned short* __restrict__ pfrag,
                        float* __restrict__ enorm) {
    const int t = threadIdx.x;
    const int lane = t & 63;
#pragma unroll
    for (int i = 0; i < 8; ++i) {
        const int f    = (i << 8) + t;
        const int code = (blockIdx.x << 5) + (f >> 6);  // wave-uniform
        const int c    = lane;
        const float v  = emb[(code << 6) + c];          // 256B coalesced
        const unsigned hb = bf16_rne(v);
        const float hf    = __uint_as_float(hb << 16);
        const unsigned lb = bf16_rne(v - hf);
        const int nc = code >> 6, grp = (code & 63) >> 4, n = code & 15;
        const int q = (c & 31) >> 3, o = c & 7;
        const int jh = c >> 5;        // eh element e=c
        const int jl = 2 + (c >> 5);  // el element e=64+c
        pfrag[((((size_t)(nc*4 + jh)*4 + grp)*4 + q)*16 + n)*8 + o] = (unsigned short)hb;
        pfrag[((((size_t)(nc*4 + jl)*4 + grp)*4 + q)*16 + n)*8 + o] = (unsigned short)lb;
        float s = v * v;
#pragma unroll
        for (int off = 32; off > 0; off >>= 1) s += __shfl_xor(s, off, 64);
        if (lane == 0) enorm[code] = s;
    }
}

// Main: 4096 blocks x 256 threads; 16 rows/block (quarter (b,h) stripe).
// Wave wv: the single 16-row M-tile x code-QUARTER wv (16 codes of each
// 64-chunk): 4 fragment loads + 6 MFMA + 4 top-2 slots per chunk.
// R13: continue the empirically-confirmed axis (R10->R11->R12: runtime
// tracks thin-wave parallelism, not L2 traffic): VGPR back to ~R11's 48,
// serial chain halved again, block queue doubled to 16/CU.
__global__ __launch_bounds__(256)
void vq_main(const float* __restrict__ x_in, const float* __restrict__ emb,
             const unsigned short* __restrict__ pfrag,
             const float* __restrict__ enorm,
             float* __restrict__ out, float* __restrict__ idx_out,
             double* __restrict__ ws_sse) {
    __shared__ float  b1s[4][16], b2s[4][16];
    __shared__ int    i1s[4][16], i2s[4][16];
    __shared__ int    c1i[16], c2i[16], qidx[16];
    __shared__ double parts[16][16];
    __shared__ double ls_red[4];

    const int t     = threadIdx.x;
    const int lane  = t & 63;
    const int wv    = t >> 6;          // code-quarter id
    const int col   = lane & 15;
    const int quad  = lane >> 4;
    const int blk   = blockIdx.x;
    const int ncol0 = wv << 4;         // code base within each 64-chunk
    const int qw   = blk & 3;          // which 16-w quarter of the stripe
    const int bh   = blk >> 2;
    const int b = bh >> 6, h = bh & 63;
    const float* xb = x_in + (size_t)b * CHW + h * 64 + (qw << 4);

    // ---- A-frags: one 16-row M-tile (row = col), direct from BCHW global
    // (coalesced), split-bf16, register-resident ----
    short8 Ah[2], Al[2];
#pragma unroll
    for (int u = 0; u < 2; ++u) {
        float f[8];
#pragma unroll
        for (int j = 0; j < 8; ++j) {
            const int c = (u << 5) + (quad << 3) + j;
            f[j] = xb[(size_t)c * HW + col];
        }
        intx4 hi, lo;
        split8(f, &hi, &lo);
        Ah[u] = __builtin_bit_cast(short8, hi);
        Al[u] = __builtin_bit_cast(short8, lo);
    }

    float B1[4], B2[4]; int I1[4], I2[4];
#pragma unroll
    for (int s = 0; s < 4; ++s) { B1[s] = FLT_BIG; B2[s] = FLT_BIG; I1[s] = 0x3FFFFFFF; I2[s] = 0x3FFFFFFF; }

    // fragment base: lane*16 within the quarter's 1 KB unit (grp = wv)
    const char* pf = (const char*)pfrag + (size_t)lane * 16 + ((size_t)wv << 10);

#pragma unroll 2
    for (int nc = 0; nc < 8; ++nc) {
        const char* base = pf + ((size_t)nc << 14);
        const int K0 = nc << 6;
        const float en = enorm[K0 + ncol0 + col];

        floatx4 a0{0.f,0.f,0.f,0.f};
#define BLD(j) (*(const short8*)(base + ((j) << 12)))
        {   // j=0: eh c[0,32) -> Ah[0] + Al[0]
            const short8 bv = BLD(0);
            a0 = __builtin_amdgcn_mfma_f32_16x16x32_bf16(Ah[0], bv, a0, 0, 0, 0);
            a0 = __builtin_amdgcn_mfma_f32_16x16x32_bf16(Al[0], bv, a0, 0, 0, 0);
        }
        {   // j=1: eh c[32,64) -> Ah[1] + Al[1]
            const short8 bv = BLD(1);
            a0 = __builtin_amdgcn_mfma_f32_16x16x32_bf16(Ah[1], bv, a0, 0, 0, 0);
            a0 = __builtin_amdgcn_mfma_f32_16x16x32_bf16(Al[1], bv, a0, 0, 0, 0);
        }
        {   // j=2: el c[0,32) -> Ah[0] only
            const short8 bv = BLD(2);
            a0 = __builtin_amdgcn_mfma_f32_16x16x32_bf16(Ah[0], bv, a0, 0, 0, 0);
        }
        {   // j=3: el c[32,64) -> Ah[1] only
            const short8 bv = BLD(3);
            a0 = __builtin_amdgcn_mfma_f32_16x16x32_bf16(Ah[1], bv, a0, 0, 0, 0);
        }
#undef BLD

        // top-2 update; codes ascend across chunks -> strict < keeps first
        // occurrence within this wave's code subset.
        const int code = K0 + ncol0 + col;
#pragma unroll
        for (int reg = 0; reg < 4; ++reg) {
            const float d = fmaf(-2.f, a0[reg], en);
            if (d < B1[reg])      { B2[reg] = B1[reg]; I2[reg] = I1[reg]; B1[reg] = d; I1[reg] = code; }
            else if (d < B2[reg]) { B2[reg] = d; I2[reg] = code; }
        }
    }

    // ---- cross-lane top-2 butterfly over col bits (xor 1..8 changes col
    // only, keeps quad -> merges the 16 codes per row-group; disjoint code
    // sets per lane, explicit index tie-break = first-occurrence) ----
#pragma unroll
    for (int off = 1; off <= 8; off <<= 1) {
#pragma unroll
        for (int s = 0; s < 4; ++s) {
            const float ob1 = __shfl_xor(B1[s], off, 64);
            const int   oi1 = __shfl_xor(I1[s], off, 64);
            const float ob2 = __shfl_xor(B2[s], off, 64);
            const int   oi2 = __shfl_xor(I2[s], off, 64);
            if (ob1 < B1[s] || (ob1 == B1[s] && oi1 < I1[s])) {
                float nb2; int ni2;
                if (B1[s] < ob2 || (B1[s] == ob2 && I1[s] < oi2)) { nb2 = B1[s]; ni2 = I1[s]; }
                else                                              { nb2 = ob2;  ni2 = oi2; }
                B1[s] = ob1; I1[s] = oi1; B2[s] = nb2; I2[s] = ni2;
            } else if (ob1 < B2[s] || (ob1 == B2[s] && oi1 < I2[s])) {
                B2[s] = ob1; I2[s] = oi1;
            }
        }
    }
    // publish per (quarter, row): row = quad*4 + reg (C/D layout); disjoint
    if (col == 0) {
#pragma unroll
        for (int s = 0; s < 4; ++s) {
            const int row = (quad << 2) + s;
            b1s[wv][row] = B1[s]; b2s[wv][row] = B2[s];
            i1s[wv][row] = I1[s]; i2s[wv][row] = I2[s];
        }
    }
    __syncthreads();

    // ---- merge the 4 quarter top-2 lists -> approx top-2 per row ----
    if (t < 16) {
        const int r = t;
        float b1 = b1s[0][r], b2 = b2s[0][r];
        int   i1 = i1s[0][r], i2 = i2s[0][r];
#pragma unroll
        for (int q = 1; q < 4; ++q) {
            const float c1 = b1s[q][r]; const int j1 = i1s[q][r];
            const float c2 = b2s[q][r]; const int j2 = i2s[q][r];
            if (c1 < b1 || (c1 == b1 && j1 < i1))      { b2 = b1; i2 = i1; b1 = c1; i1 = j1; }
            else if (c1 < b2 || (c1 == b2 && j1 < i2)) { b2 = c1; i2 = j1; }
            if (c2 < b2 || (c2 == b2 && j2 < i2))      { b2 = c2; i2 = j2; }
        }
        c1i[r] = i1; c2i[r] = i2;
    }
    __syncthreads();

    // ---- unconditional 16-way-parallel exact fp64 verify of both candidates:
    // group k = t>>4 -> candidate (k&1), c-eighth (k>>1), 8 c's each ----
    {
        const int r  = t & 15;
        const int k  = t >> 4;
        const int ce = k >> 1;
        const int code = (k & 1) ? c2i[r] : c1i[r];
        const float* ep = emb + ((size_t)code << 6) + (ce << 3);
        const float* xq = xb + r;   // lanes r consecutive -> coalesced
        double d0 = 0.0, d1 = 0.0;
#pragma unroll
        for (int cc = 0; cc < 8; cc += 2) {
            const int c = (ce << 3) + cc;
            const double f0 = (double)xq[(size_t)c * HW]       - (double)ep[cc];
            const double f1 = (double)xq[(size_t)(c + 1) * HW] - (double)ep[cc + 1];
            d0 = fma(f0, f0, d0);
            d1 = fma(f1, f1, d1);
        }
        parts[k][r] = d0 + d1;
    }
    __syncthreads();
    if (t < 16) {
        double d1 = 0.0, d2 = 0.0;
#pragma unroll
        for (int k = 0; k < 16; k += 2) {
            d1 += parts[k][t];
            d2 += parts[k + 1][t];
        }
        int i1 = c1i[t];
        const int i2 = c2i[t];
        if (d2 < d1 || (d2 == d1 && i2 < i1)) i1 = i2; // lowest-index tie-break
        qidx[t] = i1;
        idx_out[(blk << 4) + t] = (float)i1;           // n = blk*16 + r
    }
    __syncthreads();

    // ---- epilogue: quantized out (coalesced along w) + per-block SSE ----
    {
        const int r  = t & 15;
        const int c0 = (t >> 4) << 2;    // 4 channels per thread-group
        const float* xp = xb + r;
        float*       op = out + (size_t)b * CHW + h * 64 + (qw << 4) + r;
        const float* eq = emb + ((size_t)qidx[r] << 6);
        float sse_local = 0.f;
#pragma unroll
        for (int cc = 0; cc < 4; ++cc) {
            const int c = c0 + cc;
            const float qc = eq[c];
            const float dx = qc - xp[(size_t)c * HW];
            sse_local = fmaf(dx, dx, sse_local);
            op[(size_t)c * HW] = qc;
        }
#pragma unroll
        for (int off = 32; off > 0; off >>= 1)
            sse_local += __shfl_down(sse_local, off, 64);
        if (lane == 0) ls_red[wv] = (double)sse_local;
        __syncthreads();
        if (t == 0)
            ws_sse[blk] = (ls_red[0] + ls_red[1]) + (ls_red[2] + ls_red[3]);  // plain store
    }
}

// hist: 16 blocks x 256 threads; LDS histogram of 4096 indices each, plain
// partial-store. Kernel-boundary ordering provides coherence (R9-proven).
__global__ void vq_hist(const float* __restrict__ idx_out,
                        unsigned* __restrict__ part) {
    __shared__ unsigned hs[512];
    const int t = threadIdx.x;
    hs[t] = 0u; hs[t + 256] = 0u;
    __syncthreads();
    const float4* ip = (const float4*)(idx_out + (blockIdx.x << 12));
#pragma unroll
    for (int i = 0; i < 4; ++i) {
        const float4 v = ip[(i << 8) + t];    // coalesced
        atomicAdd(&hs[(int)v.x], 1u);         // LDS atomics
        atomicAdd(&hs[(int)v.y], 1u);
        atomicAdd(&hs[(int)v.z], 1u);
        atomicAdd(&hs[(int)v.w], 1u);
    }
    __syncthreads();
    unsigned* pp = part + (blockIdx.x << 9);
    pp[t] = hs[t]; pp[t + 256] = hs[t + 256];  // coalesced plain stores
}

// scal: 1 block x 512 threads. Partial hists -> perplexity; ws_sse ->
// commitment; weight -> active codes.
__global__ void vq_scal(const unsigned* __restrict__ part,
                        const double* __restrict__ ws_sse,
                        const float* __restrict__ weight,
                        float* __restrict__ scal) {
    __shared__ double redt[8], reds[8];
    __shared__ int    redi[8];
    const int k = threadIdx.x;       // 0..511 = code
    const int lane = k & 63, wv = k >> 6;
    unsigned cnt = 0;
#pragma unroll
    for (int p = 0; p < 16; ++p) cnt += part[(p << 9) + k];   // coalesced per p
    const double pr = (double)cnt / 65536.0;
    double term = pr * log(pr + 1e-10);
    double ssep = 0.0;
#pragma unroll
    for (int j = 0; j < 8; ++j) ssep += ws_sse[k + (j << 9)];
    int act = (weight[k] >= 0.01f) ? 1 : 0;
#pragma unroll
    for (int off = 32; off > 0; off >>= 1) {
        term += __shfl_down(term, off, 64);
        ssep += __shfl_down(ssep, off, 64);
        act  += __shfl_down(act,  off, 64);
    }
    if (lane == 0) { redt[wv] = term; reds[wv] = ssep; redi[wv] = act; }
    __syncthreads();
    if (k == 0) {
        double s = 0.0, ss = 0.0; int a = 0;
#pragma unroll
        for (int i = 0; i < 8; ++i) { s += redt[i]; ss += reds[i]; a += redi[i]; }
        scal[0] = (float)(ss / 4194304.0);  // commitment_loss
        scal[1] = (float)exp(-s);           // perplexity
        scal[2] = (float)a;                 // active_codes
    }
}

extern "C" void kernel_launch(void* const* d_in, const int* in_sizes, int n_in,
                              void* d_out, int out_size, void* d_ws, size_t ws_size,
                              hipStream_t stream) {
    const float* x      = (const float*)d_in[0];  // [16,64,64,64] fp32
    const float* emb    = (const float*)d_in[1];  // [512,64] fp32
    const float* weight = (const float*)d_in[2];  // [512] fp32

    float* out = (float*)d_out;
    float*          enorm  = (float*)d_ws;
    unsigned short* pfrag  = (unsigned short*)((char*)d_ws + 4096);
    double*         ws_sse = (double*)((char*)d_ws + 135168);
    unsigned*       part   = (unsigned*)((char*)d_ws + 167936);

    float* scal    = out + OUT_ELEMS;      // commitment, perplexity, active
    float* idx_out = out + OUT_ELEMS + 3;  // indices as float [65536]

    vq_prep<<<16, 256, 0, stream>>>(emb, pfrag, enorm);
    vq_main<<<4096, 256, 0, stream>>>(x, emb, pfrag, enorm, out, idx_out, ws_sse);
    vq_hist<<<16, 256, 0, stream>>>(idx_out, part);
    vq_scal<<<1, 512, 0, stream>>>(part, ws_sse, weight, scal);
}

// Round 14
// 122.781 us; speedup vs baseline: 1.1875x; 1.0460x over previous
//
#include <hip/hip_runtime.h>

// Problem constants
#define HW 4096           // H*W
#define CHW 262144        // C*H*W
#define OUT_ELEMS 4194304 // B*C*H*W
#define FLT_BIG 3.4e38f

typedef __attribute__((ext_vector_type(8))) short  short8;   // MFMA A/B frag (4 VGPR)
typedef __attribute__((ext_vector_type(4))) float  floatx4;  // MFMA C/D frag
typedef __attribute__((ext_vector_type(4))) int    intx4;

// ws layout (no zero-init needed -- every byte read is written first):
//   [0,2048)        enorm f32[512]
//   [4096,135168)   planes_frag u16 (128 KB, fragment-major split-bf16 codebook)
//   [135168,151552) ws_sse double[2048]  (per-block SSE, plain stores)
//   [151552,184320) part u32[16][512]    (per-hist-block partial histograms)

__device__ __forceinline__ unsigned bf16_rne(float f) {
    unsigned u = __float_as_uint(f);
    return (u + 0x7FFFu + ((u >> 16) & 1u)) >> 16;  // RNE bf16 bits
}

__device__ __forceinline__ void split8(const float* f, intx4* hi, intx4* lo) {
    unsigned h[4], l[4];
#pragma unroll
    for (int j = 0; j < 4; ++j) {
        const unsigned h0 = bf16_rne(f[2 * j]);
        const unsigned h1 = bf16_rne(f[2 * j + 1]);
        const float hf0 = __uint_as_float(h0 << 16);
        const float hf1 = __uint_as_float(h1 << 16);
        const unsigned l0 = bf16_rne(f[2 * j] - hf0);
        const unsigned l1 = bf16_rne(f[2 * j + 1] - hf1);
        h[j] = h0 | (h1 << 16);
        l[j] = l0 | (l1 << 16);
    }
    *hi = intx4{(int)h[0], (int)h[1], (int)h[2], (int)h[3]};
    *lo = intx4{(int)l[0], (int)l[1], (int)l[2], (int)l[3]};
}

// prep: 16 blocks x 256 threads; 32 codes/block. Fragment-major split-bf16
// codebook + exact fp32 enorm. (Unchanged since R9.)
__global__ void vq_prep(const float* __restrict__ emb,
                        unsigned short* __restrict__ pfrag,
                        float* __restrict__ enorm) {
    const int t = threadIdx.x;
    const int lane = t & 63;
#pragma unroll
    for (int i = 0; i < 8; ++i) {
        const int f    = (i << 8) + t;
        const int code = (blockIdx.x << 5) + (f >> 6);  // wave-uniform
        const int c    = lane;
        const float v  = emb[(code << 6) + c];          // 256B coalesced
        const unsigned hb = bf16_rne(v);
        const float hf    = __uint_as_float(hb << 16);
        const unsigned lb = bf16_rne(v - hf);
        const int nc = code >> 6, grp = (code & 63) >> 4, n = code & 15;
        const int q = (c & 31) >> 3, o = c & 7;
        const int jh = c >> 5;        // eh element e=c
        const int jl = 2 + (c >> 5);  // el element e=64+c
        pfrag[((((size_t)(nc*4 + jh)*4 + grp)*4 + q)*16 + n)*8 + o] = (unsigned short)hb;
        pfrag[((((size_t)(nc*4 + jl)*4 + grp)*4 + q)*16 + n)*8 + o] = (unsigned short)lb;
        float s = v * v;
#pragma unroll
        for (int off = 32; off > 0; off >>= 1) s += __shfl_xor(s, off, 64);
        if (lane == 0) enorm[code] = s;
    }
}

// Main: 2048 blocks x 256 threads; 32 rows/block (half a (b,h) stripe).
// Wave wv: 16-row M-tile (wv>>1), code-half (wv&1). K-loop byte-identical to
// R11 (best measured: 50 us). R14 changes ONLY the post-K-loop phases:
//   - butterfly (300+ instr x 256 thr) -> LDS publish + 64-thread scan-merge
//   - unconditional fp64 verify -> conditional sparse rescue (gap < 0.05;
//     split-3-term noise bound ~0.01)
__global__ __launch_bounds__(256)
void vq_main(const float* __restrict__ x_in, const float* __restrict__ emb,
             const unsigned short* __restrict__ pfrag,
             const float* __restrict__ enorm,
             float* __restrict__ out, float* __restrict__ idx_out,
             double* __restrict__ ws_sse) {
    __shared__ float4 cand[64 * 17];   // [khalf*32+row][col], stride 17 f4 (bank-optimal)
    __shared__ int    qidx[32];
    __shared__ double ls_red[4];

    const int t     = threadIdx.x;
    const int lane  = t & 63;
    const int wv    = t >> 6;
    const int col   = lane & 15;
    const int quad  = lane >> 4;
    const int blk   = blockIdx.x;
    const int mrow0 = (wv >> 1) << 4;   // wave row base (0/16)
    const int khalf = wv & 1;           // code-half of each 64-chunk
    const int ncol0 = khalf << 5;
    const int half = blk & 1;           // which 32-w half of the stripe
    const int bh = blk >> 1;
    const int b = bh >> 6, h = bh & 63;
    const float* xb = x_in + (size_t)b * CHW + h * 64 + (half << 5);

    // ---- A-frags: one 16-row M-tile, direct from BCHW global (coalesced),
    // split-bf16, register-resident (R11-identical) ----
    short8 Ah[2], Al[2];
#pragma unroll
    for (int u = 0; u < 2; ++u) {
        float f[8];
#pragma unroll
        for (int j = 0; j < 8; ++j) {
            const int c = (u << 5) + (quad << 3) + j;
            f[j] = xb[(size_t)c * HW + mrow0 + col];
        }
        intx4 hi, lo;
        split8(f, &hi, &lo);
        Ah[u] = __builtin_bit_cast(short8, hi);
        Al[u] = __builtin_bit_cast(short8, lo);
    }

    float B1[4], B2[4]; int I1[4], I2[4];
#pragma unroll
    for (int s = 0; s < 4; ++s) { B1[s] = FLT_BIG; B2[s] = FLT_BIG; I1[s] = 0x3FFFFFFF; I2[s] = 0x3FFFFFFF; }

    const char* pf = (const char*)pfrag + (size_t)lane * 16 + ((size_t)khalf << 11);

#pragma unroll 2
    for (int nc = 0; nc < 8; ++nc) {
        const char* base = pf + ((size_t)nc << 14);
        const int K0 = nc << 6;
        const float en0 = enorm[K0 + ncol0 + col];
        const float en1 = enorm[K0 + ncol0 + 16 + col];

        floatx4 a0{0.f,0.f,0.f,0.f}, a1{0.f,0.f,0.f,0.f};
#define BLD(j, g) (*(const short8*)(base + ((j) << 12) + ((g) << 10)))
        {   // j=0: eh c[0,32) -> Ah[0] + Al[0]
            const short8 b0 = BLD(0, 0), b1 = BLD(0, 1);
            a0 = __builtin_amdgcn_mfma_f32_16x16x32_bf16(Ah[0], b0, a0, 0, 0, 0);
            a1 = __builtin_amdgcn_mfma_f32_16x16x32_bf16(Ah[0], b1, a1, 0, 0, 0);
            a0 = __builtin_amdgcn_mfma_f32_16x16x32_bf16(Al[0], b0, a0, 0, 0, 0);
            a1 = __builtin_amdgcn_mfma_f32_16x16x32_bf16(Al[0], b1, a1, 0, 0, 0);
        }
        {   // j=1: eh c[32,64) -> Ah[1] + Al[1]
            const short8 b0 = BLD(1, 0), b1 = BLD(1, 1);
            a0 = __builtin_amdgcn_mfma_f32_16x16x32_bf16(Ah[1], b0, a0, 0, 0, 0);
            a1 = __builtin_amdgcn_mfma_f32_16x16x32_bf16(Ah[1], b1, a1, 0, 0, 0);
            a0 = __builtin_amdgcn_mfma_f32_16x16x32_bf16(Al[1], b0, a0, 0, 0, 0);
            a1 = __builtin_amdgcn_mfma_f32_16x16x32_bf16(Al[1], b1, a1, 0, 0, 0);
        }
        {   // j=2: el c[0,32) -> Ah[0] only
            const short8 b0 = BLD(2, 0), b1 = BLD(2, 1);
            a0 = __builtin_amdgcn_mfma_f32_16x16x32_bf16(Ah[0], b0, a0, 0, 0, 0);
            a1 = __builtin_amdgcn_mfma_f32_16x16x32_bf16(Ah[0], b1, a1, 0, 0, 0);
        }
        {   // j=3: el c[32,64) -> Ah[1] only
            const short8 b0 = BLD(3, 0), b1 = BLD(3, 1);
            a0 = __builtin_amdgcn_mfma_f32_16x16x32_bf16(Ah[1], b0, a0, 0, 0, 0);
            a1 = __builtin_amdgcn_mfma_f32_16x16x32_bf16(Ah[1], b1, a1, 0, 0, 0);
        }
#undef BLD

        // top-2 update; slot = reg (both nt codes belong to row quad*4+reg);
        // nt inner then nc outer ascends -> strict < keeps first occurrence.
#pragma unroll
        for (int nt = 0; nt < 2; ++nt) {
            const int code = K0 + ncol0 + (nt << 4) + col;
            const float en = nt ? en1 : en0;
            const floatx4 av = nt ? a1 : a0;
#pragma unroll
            for (int reg = 0; reg < 4; ++reg) {
                const float d = fmaf(-2.f, av[reg], en);
                if (d < B1[reg])      { B2[reg] = B1[reg]; I2[reg] = I1[reg]; B1[reg] = d; I1[reg] = code; }
                else if (d < B2[reg]) { B2[reg] = d; I2[reg] = code; }
            }
        }
    }

    // ---- publish per (khalf, row, col) list: one b128 per slot.
    // Address audit: per-s writes hit 256 distinct dwords spread 8x over all
    // 32 banks = the 8-clk floor, zero extra conflicts. ----
#pragma unroll
    for (int s = 0; s < 4; ++s) {
        const int row = mrow0 + (quad << 2) + s;   // C/D: row = quad*4 + reg
        cand[((khalf << 5) | row) * 17 + col] =
            make_float4(B1[s], __int_as_float(I1[s]), B2[s], __int_as_float(I2[s]));
    }
    __syncthreads();

    // ---- 64-thread scan-merge (2 threads/row, one per khalf) + sparse fp64
    // rescue + index write. Waves 1-3 idle at the barrier (their issue slots
    // go to the other resident blocks). ----
    if (t < 64) {
        const int r  = t & 31;
        const int kh = t >> 5;
        const float4* cp = &cand[((kh << 5) | r) * 17];
        float b1 = FLT_BIG, b2 = FLT_BIG; int i1 = 0x3FFFFFFF, i2 = 0x3FFFFFFF;
#pragma unroll 4
        for (int c = 0; c < 16; ++c) {
            const float4 v = cp[c];
            const float c1 = v.x; const int j1 = __float_as_int(v.y);
            const float c2 = v.z; const int j2 = __float_as_int(v.w);
            if (c1 < b1 || (c1 == b1 && j1 < i1))      { b2 = b1; i2 = i1; b1 = c1; i1 = j1; }
            else if (c1 < b2 || (c1 == b2 && j1 < i2)) { b2 = c1; i2 = j1; }
            if (c2 < b2 || (c2 == b2 && j2 < i2))      { b2 = c2; i2 = j2; }
        }
        // cross-half exchange: lanes t and t^32 hold the same row's halves
        const float ob1 = __shfl_xor(b1, 32, 64);
        const int   oi1 = __shfl_xor(i1, 32, 64);
        const float ob2 = __shfl_xor(b2, 32, 64);
        const int   oi2 = __shfl_xor(i2, 32, 64);
        if (ob1 < b1 || (ob1 == b1 && oi1 < i1))      { b2 = b1; i2 = i1; b1 = ob1; i1 = oi1; }
        else if (ob1 < b2 || (ob1 == b2 && oi1 < i2)) { b2 = ob1; i2 = oi1; }
        if (ob2 < b2 || (ob2 == b2 && oi2 < i2))      { b2 = ob2; i2 = oi2; }

        if (t < 32) {
            // sparse rescue: split-3-term noise bound ~0.01 abs; 5x margin.
            // Divergent only within wave 0; expected ~2-4 rows/block.
            if (b2 - b1 < 0.05f) {
                const float* xp  = xb + r;
                const float* e1p = emb + ((size_t)i1 << 6);
                const float* e2p = emb + ((size_t)i2 << 6);
                double d1 = 0.0, d2 = 0.0;
                for (int c = 0; c < 64; ++c) {
                    const double xv = (double)xp[(size_t)c * HW];
                    const double f1 = xv - (double)e1p[c];
                    const double f2 = xv - (double)e2p[c];
                    d1 = fma(f1, f1, d1);
                    d2 = fma(f2, f2, d2);
                }
                if (d2 < d1 || (d2 == d1 && i2 < i1)) i1 = i2;  // exact, lowest-idx ties
            }
            qidx[r] = i1;
            idx_out[(blk << 5) + r] = (float)i1;
        }
    }
    __syncthreads();

    // ---- epilogue: quantized out (coalesced along w) + per-block SSE
    // (R11-identical) ----
    {
        const int r  = t & 31;
        const int c0 = (t >> 5) << 3;    // 8 channels per thread-group
        const float* xp = xb + r;
        float*       op = out + (size_t)b * CHW + h * 64 + (half << 5) + r;
        const float* eq = emb + ((size_t)qidx[r] << 6);
        float sse_local = 0.f;
#pragma unroll
        for (int cc = 0; cc < 8; ++cc) {
            const int c = c0 + cc;
            const float qc = eq[c];
            const float dx = qc - xp[(size_t)c * HW];
            sse_local = fmaf(dx, dx, sse_local);
            op[(size_t)c * HW] = qc;
        }
#pragma unroll
        for (int off = 32; off > 0; off >>= 1)
            sse_local += __shfl_down(sse_local, off, 64);
        if (lane == 0) ls_red[wv] = (double)sse_local;
        __syncthreads();
        if (t == 0)
            ws_sse[blk] = (ls_red[0] + ls_red[1]) + (ls_red[2] + ls_red[3]);  // plain store
    }
}

// hist: 16 blocks x 256 threads; LDS histogram of 4096 indices each, plain
// partial-store. Kernel-boundary ordering provides coherence (R9-proven).
__global__ void vq_hist(const float* __restrict__ idx_out,
                        unsigned* __restrict__ part) {
    __shared__ unsigned hs[512];
    const int t = threadIdx.x;
    hs[t] = 0u; hs[t + 256] = 0u;
    __syncthreads();
    const float4* ip = (const float4*)(idx_out + (blockIdx.x << 12));
#pragma unroll
    for (int i = 0; i < 4; ++i) {
        const float4 v = ip[(i << 8) + t];    // coalesced
        atomicAdd(&hs[(int)v.x], 1u);         // LDS atomics
        atomicAdd(&hs[(int)v.y], 1u);
        atomicAdd(&hs[(int)v.z], 1u);
        atomicAdd(&hs[(int)v.w], 1u);
    }
    __syncthreads();
    unsigned* pp = part + (blockIdx.x << 9);
    pp[t] = hs[t]; pp[t + 256] = hs[t + 256];  // coalesced plain stores
}

// scal: 1 block x 512 threads. Partial hists -> perplexity; ws_sse ->
// commitment; weight -> active codes.
__global__ void vq_scal(const unsigned* __restrict__ part,
                        const double* __restrict__ ws_sse,
                        const float* __restrict__ weight,
                        float* __restrict__ scal) {
    __shared__ double redt[8], reds[8];
    __shared__ int    redi[8];
    const int k = threadIdx.x;       // 0..511 = code
    const int lane = k & 63, wv = k >> 6;
    unsigned cnt = 0;
#pragma unroll
    for (int p = 0; p < 16; ++p) cnt += part[(p << 9) + k];   // coalesced per p
    const double pr = (double)cnt / 65536.0;
    double term = pr * log(pr + 1e-10);
    double ssep = 0.0;
#pragma unroll
    for (int j = 0; j < 4; ++j) ssep += ws_sse[k + (j << 9)];
    int act = (weight[k] >= 0.01f) ? 1 : 0;
#pragma unroll
    for (int off = 32; off > 0; off >>= 1) {
        term += __shfl_down(term, off, 64);
        ssep += __shfl_down(ssep, off, 64);
        act  += __shfl_down(act,  off, 64);
    }
    if (lane == 0) { redt[wv] = term; reds[wv] = ssep; redi[wv] = act; }
    __syncthreads();
    if (k == 0) {
        double s = 0.0, ss = 0.0; int a = 0;
#pragma unroll
        for (int i = 0; i < 8; ++i) { s += redt[i]; ss += reds[i]; a += redi[i]; }
        scal[0] = (float)(ss / 4194304.0);  // commitment_loss
        scal[1] = (float)exp(-s);           // perplexity
        scal[2] = (float)a;                 // active_codes
    }
}

extern "C" void kernel_launch(void* const* d_in, const int* in_sizes, int n_in,
                              void* d_out, int out_size, void* d_ws, size_t ws_size,
                              hipStream_t stream) {
    const float* x      = (const float*)d_in[0];  // [16,64,64,64] fp32
    const float* emb    = (const float*)d_in[1];  // [512,64] fp32
    const float* weight = (const float*)d_in[2];  // [512] fp32

    float* out = (float*)d_out;
    float*          enorm  = (float*)d_ws;
    unsigned short* pfrag  = (unsigned short*)((char*)d_ws + 4096);
    double*         ws_sse = (double*)((char*)d_ws + 135168);
    unsigned*       part   = (unsigned*)((char*)d_ws + 151552);

    float* scal    = out + OUT_ELEMS;      // commitment, perplexity, active
    float* idx_out = out + OUT_ELEMS + 3;  // indices as float [65536]

    vq_prep<<<16, 256, 0, stream>>>(emb, pfrag, enorm);
    vq_main<<<2048, 256, 0, stream>>>(x, emb, pfrag, enorm, out, idx_out, ws_sse);
    vq_hist<<<16, 256, 0, stream>>>(idx_out, part);
    vq_scal<<<1, 512, 0, stream>>>(part, ws_sse, weight, scal);
}